// Round 1
// baseline (93.279 us; speedup 1.0000x reference)
//
#include <hip/hip_runtime.h>
#include <hip/hip_bf16.h>
#include <cstdint>

// Problem: N=8192, F=256. out = D^-1/2 (I+A) D^-1/2 X W + b
// A is dense f32 0/1, ~33 nnz/row. Strategy: extract sparse structure (ELL),
// dense f32 GEMM for Y=X@W, then sparse gather-accumulate.

#define NN 8192
#define FF 256
#define ELLK 128   // max nnz slots per row; deg ~ Binom(8191, 0.004), mean 33, 16 sigma to 128

// ---------------- Kernel 1: scan A rows -> ELL indices, degree, d = rsqrt(deg+1) ----
__global__ __launch_bounds__(256) void ascan_kernel(const float* __restrict__ A,
                                                    float* __restrict__ dvals,
                                                    int* __restrict__ nnz,
                                                    unsigned short* __restrict__ ell) {
    __shared__ int cnt;
    __shared__ unsigned short loc[ELLK];
    const int row = blockIdx.x;
    if (threadIdx.x == 0) cnt = 0;
    __syncthreads();
    const float4* Arow = reinterpret_cast<const float4*>(A + (size_t)row * NN);
    #pragma unroll
    for (int k = 0; k < 8; ++k) {
        int idx4 = k * 256 + threadIdx.x;       // 0..2047, coalesced float4
        float4 v = Arow[idx4];
        int base = idx4 * 4;
        if (v.x != 0.0f) { int p = atomicAdd(&cnt, 1); if (p < ELLK) loc[p] = (unsigned short)(base + 0); }
        if (v.y != 0.0f) { int p = atomicAdd(&cnt, 1); if (p < ELLK) loc[p] = (unsigned short)(base + 1); }
        if (v.z != 0.0f) { int p = atomicAdd(&cnt, 1); if (p < ELLK) loc[p] = (unsigned short)(base + 2); }
        if (v.w != 0.0f) { int p = atomicAdd(&cnt, 1); if (p < ELLK) loc[p] = (unsigned short)(base + 3); }
    }
    __syncthreads();
    int c = cnt < ELLK ? cnt : ELLK;
    for (int t = threadIdx.x; t < c; t += 256)
        ell[(size_t)row * ELLK + t] = loc[t];
    if (threadIdx.x == 0) {
        nnz[row] = c;
        dvals[row] = 1.0f / sqrtf((float)(c + 1));   // self-loop adds 1
    }
}

// ---------------- Kernel 2: Y = X @ W (f32, 64x64x16 tiles, 4x4 microtiles) --------
#define BM 64
#define BN 64
#define BK 16
__global__ __launch_bounds__(256) void gemm_xw_kernel(const float* __restrict__ X,
                                                      const float* __restrict__ W,
                                                      float* __restrict__ Y) {
    __shared__ float As[BK][BM + 4];   // +4 keeps 16B alignment, breaks pow2 stride
    __shared__ float Bs[BK][BN];
    const int m0 = blockIdx.x * BM;
    const int n0 = blockIdx.y * BN;
    const int tid = threadIdx.x;
    const int tr = tid / 16;     // 0..15
    const int tc = tid % 16;     // 0..15
    float acc[4][4] = {};
    for (int k0 = 0; k0 < FF; k0 += BK) {
        {   // A tile: 64 rows x 16 k; each thread: float4 along k
            int r  = tid / 4;            // 0..63
            int kq = (tid % 4) * 4;      // 0,4,8,12
            float4 v = *reinterpret_cast<const float4*>(X + (size_t)(m0 + r) * FF + k0 + kq);
            As[kq + 0][r] = v.x; As[kq + 1][r] = v.y; As[kq + 2][r] = v.z; As[kq + 3][r] = v.w;
        }
        {   // B tile: 16 k x 64 n; each thread: float4 along n
            int kk = tid / 16;           // 0..15
            int nq = (tid % 16) * 4;     // 0..60
            float4 v = *reinterpret_cast<const float4*>(W + (size_t)(k0 + kk) * FF + n0 + nq);
            *reinterpret_cast<float4*>(&Bs[kk][nq]) = v;
        }
        __syncthreads();
        #pragma unroll
        for (int kk = 0; kk < BK; ++kk) {
            float a[4], b[4];
            #pragma unroll
            for (int i = 0; i < 4; ++i) a[i] = As[kk][tr * 4 + i];
            #pragma unroll
            for (int j = 0; j < 4; ++j) b[j] = Bs[kk][tc * 4 + j];
            #pragma unroll
            for (int i = 0; i < 4; ++i)
                #pragma unroll
                for (int j = 0; j < 4; ++j)
                    acc[i][j] = fmaf(a[i], b[j], acc[i][j]);
        }
        __syncthreads();
    }
    #pragma unroll
    for (int i = 0; i < 4; ++i) {
        float4 v = { acc[i][0], acc[i][1], acc[i][2], acc[i][3] };
        *reinterpret_cast<float4*>(Y + (size_t)(m0 + tr * 4 + i) * FF + n0 + tc * 4) = v;
    }
}

// ---------------- Kernel 3: out[i,:] = d_i*(d_i*Y[i,:] + sum_j d_j*Y[j,:]) + b -----
__global__ __launch_bounds__(256) void spmm_kernel(const float* __restrict__ Y,
                                                   const float* __restrict__ dvals,
                                                   const int* __restrict__ nnz,
                                                   const unsigned short* __restrict__ ell,
                                                   const float* __restrict__ bias,
                                                   float* __restrict__ out) {
    const int row = blockIdx.x;
    const int f = threadIdx.x;           // feature
    __shared__ int   lidx[ELLK];
    __shared__ float ldj[ELLK];
    const int c = nnz[row];              // broadcast load, same addr all lanes
    if (f < c) {
        int j = ell[(size_t)row * ELLK + f];
        lidx[f] = j;
        ldj[f]  = dvals[j];
    }
    __syncthreads();
    const float di = dvals[row];
    float acc = di * Y[(size_t)row * FF + f];     // self loop
    for (int t = 0; t < c; ++t) {
        acc = fmaf(ldj[t], Y[(size_t)lidx[t] * FF + f], acc);
    }
    out[(size_t)row * FF + f] = fmaf(di, acc, bias[f]);
}

extern "C" void kernel_launch(void* const* d_in, const int* in_sizes, int n_in,
                              void* d_out, int out_size, void* d_ws, size_t ws_size,
                              hipStream_t stream) {
    const float* A    = (const float*)d_in[0];   // [8192,8192]
    const float* X    = (const float*)d_in[1];   // [8192,256]
    const float* W    = (const float*)d_in[2];   // [256,256]
    const float* bias = (const float*)d_in[3];   // [256]
    float* out = (float*)d_out;                  // [8192,256]

    // workspace layout (needs ~10.1 MB)
    char* ws = (char*)d_ws;
    float*          Y     = (float*)(ws);                               // 8 MiB
    float*          dvals = (float*)(ws + (size_t)NN * FF * 4);         // 32 KiB
    int*            nnz   = (int*)(ws + (size_t)NN * FF * 4 + NN * 4);  // 32 KiB
    unsigned short* ell   = (unsigned short*)(ws + (size_t)NN * FF * 4 + NN * 8); // 2 MiB

    // 1) scan A -> sparse structure + degrees (HBM-bound, ~256 MiB read)
    ascan_kernel<<<NN, 256, 0, stream>>>(A, dvals, nnz, ell);
    // 2) Y = X @ W  (independent of 1)
    gemm_xw_kernel<<<dim3(NN / BM, FF / BN), 256, 0, stream>>>(X, W, Y);
    // 3) normalized sparse aggregation + bias
    spmm_kernel<<<NN, 256, 0, stream>>>(Y, dvals, nnz, ell, bias, out);
}

// Round 2
// 65.273 us; speedup vs baseline: 1.4291x; 1.4291x over previous
//
#include <hip/hip_runtime.h>
#include <hip/hip_bf16.h>
#include <cstdint>

// out = D^-1/2 (I+A) D^-1/2 X W + b ; N=8192, F=256, ~33 nnz/row.
// Stage 1 (fused): [GEMM Y=X@W -> bf16]  ||  [A-scan -> ELL + degrees]
//   - GEMM blocks first in grid so they're resident immediately and run in
//     the HBM shadow of the A stream (separate pipes: VALU vs VMEM).
// Stage 2: wave-per-row gather: out[i] = d_i*(d_i*Y[i] + sum_j d_j*Y[j]) + b
//   - Y in bf16 (4 MiB, L2-resident), ushort4 loads (8B/lane).

#define NN 8192
#define FF 256
#define ELLK 128           // deg ~ Binom(8191,0.004): mean 33, sd 5.7 -> 16 sigma
#define BM 64
#define BN 64
#define BK 16
#define NGEMM ((NN / BM) * (FF / BN))   // 512 gemm blocks

__device__ __forceinline__ float bf2f(unsigned short u) {
    union { unsigned int i; float f; } c; c.i = ((unsigned int)u) << 16; return c.f;
}
__device__ __forceinline__ unsigned short f2bf(float f) {
    union { float f; unsigned int i; } c; c.f = f;
    unsigned int r = c.i + 0x7FFF + ((c.i >> 16) & 1);   // round-to-nearest-even
    return (unsigned short)(r >> 16);
}

__global__ __launch_bounds__(256) void fused_stage1(const float* __restrict__ A,
                                                    const float* __restrict__ X,
                                                    const float* __restrict__ W,
                                                    unsigned short* __restrict__ Yb,
                                                    float* __restrict__ dvals,
                                                    int* __restrict__ nnz,
                                                    unsigned short* __restrict__ ell) {
    if (blockIdx.x < NGEMM) {
        // ---------------- GEMM: Y = X @ W, f32 accum, bf16 out ----------------
        __shared__ float As[BK][BM + 4];
        __shared__ float Bs[BK][BN];
        const int bid = blockIdx.x;
        const int m0 = (bid / (FF / BN)) * BM;
        const int n0 = (bid % (FF / BN)) * BN;
        const int tid = threadIdx.x;
        const int tr = tid / 16;     // 0..15
        const int tc = tid % 16;     // 0..15
        float acc[4][4] = {};
        for (int k0 = 0; k0 < FF; k0 += BK) {
            {   // X tile: 64 rows x 16 k
                int r  = tid / 4;
                int kq = (tid % 4) * 4;
                float4 v = *reinterpret_cast<const float4*>(X + (size_t)(m0 + r) * FF + k0 + kq);
                As[kq + 0][r] = v.x; As[kq + 1][r] = v.y; As[kq + 2][r] = v.z; As[kq + 3][r] = v.w;
            }
            {   // W tile: 16 k x 64 n
                int kk = tid / 16;
                int nq = (tid % 16) * 4;
                float4 v = *reinterpret_cast<const float4*>(W + (size_t)(k0 + kk) * FF + n0 + nq);
                *reinterpret_cast<float4*>(&Bs[kk][nq]) = v;
            }
            __syncthreads();
            #pragma unroll
            for (int kk = 0; kk < BK; ++kk) {
                float a[4], b[4];
                #pragma unroll
                for (int i = 0; i < 4; ++i) a[i] = As[kk][tr * 4 + i];
                #pragma unroll
                for (int j = 0; j < 4; ++j) b[j] = Bs[kk][tc * 4 + j];
                #pragma unroll
                for (int i = 0; i < 4; ++i)
                    #pragma unroll
                    for (int j = 0; j < 4; ++j)
                        acc[i][j] = fmaf(a[i], b[j], acc[i][j]);
            }
            __syncthreads();
        }
        #pragma unroll
        for (int i = 0; i < 4; ++i) {
            ushort4 v = { f2bf(acc[i][0]), f2bf(acc[i][1]), f2bf(acc[i][2]), f2bf(acc[i][3]) };
            *reinterpret_cast<ushort4*>(Yb + (size_t)(m0 + tr * 4 + i) * FF + n0 + tc * 4) = v;
        }
    } else {
        // ---------------- A-scan: ELL indices + degree + d = rsqrt(deg+1) -----
        __shared__ int cnt;
        __shared__ unsigned short loc[ELLK];
        const int row = blockIdx.x - NGEMM;
        if (threadIdx.x == 0) cnt = 0;
        __syncthreads();
        const uint4* Arow = reinterpret_cast<const uint4*>(A + (size_t)row * NN);
        #pragma unroll
        for (int k = 0; k < 8; ++k) {
            int idx4 = k * 256 + threadIdx.x;       // coalesced 16B
            uint4 v = Arow[idx4];
            int base = idx4 * 4;
            if (v.x) { int p = atomicAdd(&cnt, 1); if (p < ELLK) loc[p] = (unsigned short)(base + 0); }
            if (v.y) { int p = atomicAdd(&cnt, 1); if (p < ELLK) loc[p] = (unsigned short)(base + 1); }
            if (v.z) { int p = atomicAdd(&cnt, 1); if (p < ELLK) loc[p] = (unsigned short)(base + 2); }
            if (v.w) { int p = atomicAdd(&cnt, 1); if (p < ELLK) loc[p] = (unsigned short)(base + 3); }
        }
        __syncthreads();
        int c = cnt < ELLK ? cnt : ELLK;
        for (int t = threadIdx.x; t < c; t += 256)
            ell[(size_t)row * ELLK + t] = loc[t];
        if (threadIdx.x == 0) {
            nnz[row] = c;
            dvals[row] = 1.0f / sqrtf((float)(c + 1));
        }
    }
}

// ---- Stage 2: wave-per-row normalized aggregation over bf16 Y ---------------
__global__ __launch_bounds__(256) void spmm_kernel(const unsigned short* __restrict__ Yb,
                                                   const float* __restrict__ dvals,
                                                   const int* __restrict__ nnz,
                                                   const unsigned short* __restrict__ ell,
                                                   const float* __restrict__ bias,
                                                   float* __restrict__ out) {
    const int wave = threadIdx.x >> 6;
    const int lane = threadIdx.x & 63;
    const int row = blockIdx.x * 4 + wave;
    __shared__ unsigned short sidx[4][ELLK];
    __shared__ float sdj[4][ELLK];
    const int c = nnz[row];
    for (int t = lane; t < c; t += 64) {
        int j = ell[(size_t)row * ELLK + t];
        sidx[wave][t] = (unsigned short)j;
        sdj[wave][t]  = dvals[j];
    }
    __syncthreads();
    const float di = dvals[row];
    ushort4 ys = *reinterpret_cast<const ushort4*>(Yb + (size_t)row * FF + lane * 4);
    float a0 = di * bf2f(ys.x), a1 = di * bf2f(ys.y);
    float a2 = di * bf2f(ys.z), a3 = di * bf2f(ys.w);
    for (int t = 0; t < c; ++t) {
        int j = sidx[wave][t];
        float dj = sdj[wave][t];
        ushort4 v = *reinterpret_cast<const ushort4*>(Yb + (size_t)j * FF + lane * 4);
        a0 = fmaf(dj, bf2f(v.x), a0);
        a1 = fmaf(dj, bf2f(v.y), a1);
        a2 = fmaf(dj, bf2f(v.z), a2);
        a3 = fmaf(dj, bf2f(v.w), a3);
    }
    float4 b4 = *reinterpret_cast<const float4*>(bias + lane * 4);
    float4 o;
    o.x = fmaf(di, a0, b4.x);
    o.y = fmaf(di, a1, b4.y);
    o.z = fmaf(di, a2, b4.z);
    o.w = fmaf(di, a3, b4.w);
    *reinterpret_cast<float4*>(out + (size_t)row * FF + lane * 4) = o;
}

extern "C" void kernel_launch(void* const* d_in, const int* in_sizes, int n_in,
                              void* d_out, int out_size, void* d_ws, size_t ws_size,
                              hipStream_t stream) {
    const float* A    = (const float*)d_in[0];   // [8192,8192]
    const float* X    = (const float*)d_in[1];   // [8192,256]
    const float* W    = (const float*)d_in[2];   // [256,256]
    const float* bias = (const float*)d_in[3];   // [256]
    float* out = (float*)d_out;                  // [8192,256]

    // workspace: Yb 4 MiB | dvals 32 KiB | nnz 32 KiB | ell 2 MiB
    char* ws = (char*)d_ws;
    unsigned short* Yb    = (unsigned short*)(ws);
    float*          dvals = (float*)(ws + (size_t)NN * FF * 2);
    int*            nnz   = (int*)(ws + (size_t)NN * FF * 2 + NN * 4);
    unsigned short* ell   = (unsigned short*)(ws + (size_t)NN * FF * 2 + NN * 8);

    fused_stage1<<<NGEMM + NN, 256, 0, stream>>>(A, X, W, Yb, dvals, nnz, ell);
    spmm_kernel<<<NN / 4, 256, 0, stream>>>(Yb, dvals, nnz, ell, bias, out);
}